// Round 8
// baseline (169.841 us; speedup 1.0000x reference)
//
#include <hip/hip_runtime.h>
#include <hip/hip_bf16.h>
#include <math.h>

typedef _Float16 f16_t;
typedef _Float16 f16x4 __attribute__((ext_vector_type(4)));
typedef _Float16 f16x8 __attribute__((ext_vector_type(8)));
typedef float f32x4 __attribute__((ext_vector_type(4)));

#define BATCH 131072
#define RPW 32                 // rows per wave
#define MTILE 128              // rows per block (4 waves)
#define NBLK (BATCH / MTILE)

// fragment-layout weight offsets in d_ws (elements, f16)
#define W1F 0
#define W2F 4096
#define W3F 20480
#define W4F 36864

// ---------------------------------------------------------------------------
// swizzled addressing
// hidden strip: 32 rows x 128 f16, G4 XOR swizzle (16B slot ^= row&7)
__device__ __forceinline__ int hsw(int r, int e) {      // e = element 0..127
  return r * 128 + (e ^ ((r & 7) << 3));
}
// x2 stage buffer: rows x 32 f16, 8B-group swizzle
__device__ __forceinline__ int xsw(int r, int e) {      // e = element 0..31
  return r * 32 + (e ^ ((r & 7) << 2));
}

// ---------------------------------------------------------------------------
// Kernel A: fp32 weights -> fp16 MFMA B-fragment layout.
//   col = tile*16 + (lane&15), k = kstep*32 + (lane>>4)*8 + j
// W4 laid out as 8 chunks x 92 cols padded to 96 (6 tiles).
// ---------------------------------------------------------------------------
__global__ __launch_bounds__(256) void convert_weights_kernel(
    const float* __restrict__ W1, const float* __restrict__ W2,
    const float* __restrict__ W3, const float* __restrict__ W4,
    f16_t* __restrict__ wf) {
  int tid = blockIdx.x * 256 + threadIdx.x;
  if (tid >= 16896) return;
  int lane = tid & 63;
  int l16 = lane & 15, lhi = lane >> 4;
  const float* W; int ncols, col, k0; bool zero = false;
  if (tid < 512) {
    int n = tid >> 6;
    W = W1; ncols = 128; col = n * 16 + l16; k0 = lhi * 8;
  } else if (tid < 2560) {
    int g = tid - 512; int n = g >> 8, s = (g >> 6) & 3;
    W = W2; ncols = 128; col = n * 16 + l16; k0 = s * 32 + lhi * 8;
  } else if (tid < 4608) {
    int g = tid - 2560; int n = g >> 8, s = (g >> 6) & 3;
    W = W3; ncols = 128; col = n * 16 + l16; k0 = s * 32 + lhi * 8;
  } else {
    int g = tid - 4608; int t = g >> 8, s = (g >> 6) & 3;
    int c = t / 6, n = t - c * 6;
    int colc = n * 16 + l16;
    W = W4; ncols = 736; col = c * 92 + colc; k0 = s * 32 + lhi * 8;
    zero = (colc >= 92);
  }
  f16x8 v;
#pragma unroll
  for (int j = 0; j < 8; ++j)
    v[j] = zero ? (f16_t)0.f : (f16_t)W[(k0 + j) * ncols + col];
  *(f16x8*)(wf + (size_t)tid * 8) = v;
}

__device__ __forceinline__ float elu(float v) {
  return v > 0.f ? v : (__expf(v) - 1.f);
}

// ---------------------------------------------------------------------------
// spline for one (row, dim) task; P = 24-f16 param slot (16B-aligned).
// No softmax max-subtract (pre-acts are O(3)); divides via v_rcp_f32.
// ---------------------------------------------------------------------------
__device__ __forceinline__ void rqs_task(const f16_t* P, float xv,
                                         float& yout, float& ldout) {
  f16x8 pw = *(const f16x8*)P;
  f16x8 ph = *(const f16x8*)(P + 8);
  f16x8 pd = *(const f16x8*)(P + 16);   // [7] is pad, unused

  float ew[8], sw = 0.f;
#pragma unroll
  for (int i = 0; i < 8; ++i) { ew[i] = __expf((float)pw[i]); sw += ew[i]; }
  float invw = 0.992f * __builtin_amdgcn_rcpf(sw);
  float cw[9]; cw[0] = -3.f;
  float accw = 0.f;
#pragma unroll
  for (int i = 0; i < 8; ++i) {
    accw += 0.001f + ew[i] * invw;
    cw[i + 1] = -3.f + 6.f * accw;
  }
  cw[8] = 3.f;
  float wd[8];
#pragma unroll
  for (int i = 0; i < 8; ++i) wd[i] = cw[i + 1] - cw[i];

  float eh[8], sh = 0.f;
#pragma unroll
  for (int i = 0; i < 8; ++i) { eh[i] = __expf((float)ph[i]); sh += eh[i]; }
  float invh = 0.992f * __builtin_amdgcn_rcpf(sh);
  float ch[9]; ch[0] = -3.f;
  float acch = 0.f;
#pragma unroll
  for (int i = 0; i < 8; ++i) {
    acch += 0.001f + eh[i] * invh;
    ch[i + 1] = -3.f + 6.f * acch;
  }
  ch[8] = 3.f;
  float ht[8];
#pragma unroll
  for (int i = 0; i < 8; ++i) ht[i] = ch[i + 1] - ch[i];

  float dd[9]; dd[0] = 1.f; dd[8] = 1.f;
#pragma unroll
  for (int i = 0; i < 7; ++i) {
    float u = (float)pd[i];
    float sp = fmaxf(u, 0.f) + __logf(1.f + __expf(-fabsf(u)));
    dd[i + 1] = 0.001f + sp;
  }

  float xc = fminf(fmaxf(xv, -3.f), 3.f);
  int bin = 0;
#pragma unroll
  for (int i = 1; i < 8; ++i) bin += (xc >= cw[i]) ? 1 : 0;

  float in_cw = cw[0], in_w = wd[0], in_ch = ch[0], in_h = ht[0];
  float in_d = dd[0], in_d1 = dd[1];
#pragma unroll
  for (int i = 1; i < 8; ++i) {
    bool g = (bin >= i);
    in_cw = g ? cw[i] : in_cw;  in_w = g ? wd[i] : in_w;
    in_ch = g ? ch[i] : in_ch;  in_h = g ? ht[i] : in_h;
    in_d  = g ? dd[i] : in_d;   in_d1 = g ? dd[i + 1] : in_d1;
  }

  float rw = __builtin_amdgcn_rcpf(in_w);
  float dlt = in_h * rw;
  float th = (xc - in_cw) * rw;
  float om = 1.f - th;
  float t1 = th * om;
  float num = in_h * (dlt * th * th + in_d * t1);
  float den = dlt + (in_d + in_d1 - 2.f * dlt) * t1;
  float rden = __builtin_amdgcn_rcpf(den);
  float yo = in_ch + num * rden;
  float dn = dlt * dlt * (in_d1 * th * th + 2.f * dlt * t1 + in_d * om * om);
  float ldv = __logf(dn * rden * rden);
  bool inside = (xv >= -3.f) && (xv <= 3.f);
  yout = inside ? yo : xv;
  ldout = inside ? ldv : 0.f;
}

// ---------------------------------------------------------------------------
// middle MLP layer, in-place on the wave's own swizzled 32-row strip.
// Both tiles' A-fragments are register-resident before the first store.
// ---------------------------------------------------------------------------
__device__ __forceinline__ void mid_layer2(f16_t* hW,
                                           const f16_t* __restrict__ wseg,
                                           const float* __restrict__ bg,
                                           int l16, int lhi, int lane) {
  f16x8 a0[4], a1[4];
#pragma unroll
  for (int s = 0; s < 4; ++s) {
    a0[s] = *(const f16x8*)&hW[hsw(l16,      s * 32 + lhi * 8)];
    a1[s] = *(const f16x8*)&hW[hsw(16 + l16, s * 32 + lhi * 8)];
  }
#pragma unroll
  for (int n = 0; n < 8; ++n) {
    f32x4 c0 = {0.f, 0.f, 0.f, 0.f}, c1 = {0.f, 0.f, 0.f, 0.f};
#pragma unroll
    for (int s = 0; s < 4; ++s) {
      f16x8 b = *(const f16x8*)(wseg + (size_t)((n * 4 + s) * 64 + lane) * 8);
      c0 = __builtin_amdgcn_mfma_f32_16x16x32_f16(a0[s], b, c0, 0, 0, 0);
      c1 = __builtin_amdgcn_mfma_f32_16x16x32_f16(a1[s], b, c1, 0, 0, 0);
    }
    float bias = bg[n * 16 + l16];
#pragma unroll
    for (int r = 0; r < 4; ++r) {
      hW[hsw(lhi * 4 + r,      n * 16 + l16)] = (f16_t)elu(c0[r] + bias);
      hW[hsw(16 + lhi * 4 + r, n * 16 + l16)] = (f16_t)elu(c1[r] + bias);
    }
  }
}

// ---------------------------------------------------------------------------
// Kernel B: fused MLP + RQS spline. 32 rows/wave, 4 waves/block, fully
// wave-independent (no __syncthreads; every LDS structure is wave-private).
// LDS = 32768 (strips) + 8192 (x2 stage) = 40960 B -> 4 blocks/CU.
// ALL global traffic is full-line: x read once, out written once.
// ---------------------------------------------------------------------------
__global__ __launch_bounds__(256, 4) void nsf_fused_kernel(
    const float* __restrict__ x,
    const float* __restrict__ b1g, const float* __restrict__ b2g,
    const float* __restrict__ b3g, const float* __restrict__ b4g,
    const f16_t* __restrict__ wf,
    float* __restrict__ out) {
  __shared__ f16_t hH[MTILE * 128];    // 4 swizzled hidden strips
  __shared__ f16_t x2g[MTILE * 32];    // staged x2 (f16, swizzled)

  const int tid = threadIdx.x;
  const int lane = tid & 63;
  const int wv = tid >> 6;
  const int l16 = lane & 15, lhi = lane >> 4;
  const int row0 = blockIdx.x * MTILE + wv * RPW;   // wave's global row base
  f16_t* hW = hH + wv * RPW * 128;                  // wave's private strip
  f16_t* x2s = x2g + wv * RPW * 32;

  // ---- stage: full x rows once. x1 -> out + strip; x2 -> x2s (f16) ----
  {
    const float4* x4 = (const float4*)(x + (size_t)row0 * 64);
    float4* o4 = (float4*)(out + (size_t)row0 * 64);
#pragma unroll
    for (int i = 0; i < 8; ++i) {
      int flat = i * 64 + lane;          // 0..511 = 32 rows x 16 float4
      int r = flat >> 4, f = flat & 15;
      float4 v = x4[r * 16 + f];
      f16x4 p = {(f16_t)v.x, (f16_t)v.y, (f16_t)v.z, (f16_t)v.w};
      if (f < 8) {                       // x1 cols 0..31
        o4[r * 16 + f] = v;
        *(f16x4*)&hW[hsw(r, f * 4)] = p;
      } else {                           // x2 cols 32..63
        *(f16x4*)&x2s[xsw(r, (f - 8) * 4)] = p;
      }
    }
  }
  __builtin_amdgcn_wave_barrier();

  // ---- layer 1: K=32, 2 row-tiles, in-place ----
  {
    f16x8 a0 = *(const f16x8*)&hW[hsw(l16,      lhi * 8)];
    f16x8 a1 = *(const f16x8*)&hW[hsw(16 + l16, lhi * 8)];
#pragma unroll
    for (int n = 0; n < 8; ++n) {
      f16x8 b = *(const f16x8*)(wf + W1F + (size_t)(n * 64 + lane) * 8);
      f32x4 c0 = {0.f, 0.f, 0.f, 0.f}, c1 = {0.f, 0.f, 0.f, 0.f};
      c0 = __builtin_amdgcn_mfma_f32_16x16x32_f16(a0, b, c0, 0, 0, 0);
      c1 = __builtin_amdgcn_mfma_f32_16x16x32_f16(a1, b, c1, 0, 0, 0);
      float bias = b1g[n * 16 + l16];
#pragma unroll
      for (int r = 0; r < 4; ++r) {
        hW[hsw(lhi * 4 + r,      n * 16 + l16)] = (f16_t)elu(c0[r] + bias);
        hW[hsw(16 + lhi * 4 + r, n * 16 + l16)] = (f16_t)elu(c1[r] + bias);
      }
    }
  }
  __builtin_amdgcn_wave_barrier();

  mid_layer2(hW, wf + W2F, b2g, l16, lhi, lane);   // layer 2
  __builtin_amdgcn_wave_barrier();
  mid_layer2(hW, wf + W3F, b3g, l16, lhi, lane);   // layer 3
  __builtin_amdgcn_wave_barrier();

  // ---- layer 4 + spline; prm + y2s alias the (now dead) strip ----
  {
    f16x8 a40[4], a41[4];
#pragma unroll
    for (int s = 0; s < 4; ++s) {
      a40[s] = *(const f16x8*)&hW[hsw(l16,      s * 32 + lhi * 8)];
      a41[s] = *(const f16x8*)&hW[hsw(16 + l16, s * 32 + lhi * 8)];
    }
    __builtin_amdgcn_wave_barrier();

    f16_t* prW = hW;             // slots: (local_row*4 + dim)*24 -> [0,3072)
    f16_t* y2s = hW + 3072;      // [32 rows][32] f16, swizzled -> [3072,4096)
    const int rl = lane >> 2, dim = lane & 3;
    float ldp0 = 0.f, ldp1 = 0.f;

    for (int c = 0; c < 8; ++c) {
      int jg = c * 4 + dim;
      float xv0 = (float)x2s[xsw(rl,      jg)];
      float xv1 = (float)x2s[xsw(rl + 16, jg)];

      // GEMM4 chunk: 92 real cols (4 dims x 23) padded to 96 (6 tiles)
#pragma unroll
      for (int n = 0; n < 6; ++n) {
        f32x4 c0 = {0.f, 0.f, 0.f, 0.f}, c1 = {0.f, 0.f, 0.f, 0.f};
#pragma unroll
        for (int s = 0; s < 4; ++s) {
          f16x8 b = *(const f16x8*)(wf + W4F +
                      (size_t)(((c * 6 + n) * 4 + s) * 64 + lane) * 8);
          c0 = __builtin_amdgcn_mfma_f32_16x16x32_f16(a40[s], b, c0, 0, 0, 0);
          c1 = __builtin_amdgcn_mfma_f32_16x16x32_f16(a41[s], b, c1, 0, 0, 0);
        }
        int colc = n * 16 + l16;
        if (colc < 92) {
          int dm = (colc * 90) >> 11;          // colc / 23 for colc < 92
          int j = colc - dm * 23;
          float bias = b4g[c * 92 + colc];
#pragma unroll
          for (int r = 0; r < 4; ++r) {
            prW[((lhi * 4 + r) * 4 + dm) * 24 + j]      = (f16_t)(c0[r] + bias);
            prW[((16 + lhi * 4 + r) * 4 + dm) * 24 + j] = (f16_t)(c1[r] + bias);
          }
        }
      }
      __builtin_amdgcn_wave_barrier();

      // two spline tasks per lane: rows rl and rl+16, dim = lane&3
      {
        float y0, l0, y1, l1;
        rqs_task(prW + (rl * 4 + dim) * 24, xv0, y0, l0);
        y2s[rl * 32 + (jg ^ ((rl & 7) << 2))] = (f16_t)y0;
        ldp0 += l0;
        rqs_task(prW + ((rl + 16) * 4 + dim) * 24, xv1, y1, l1);
        y2s[(rl + 16) * 32 + (jg ^ ((rl & 7) << 2))] = (f16_t)y1;
        ldp1 += l1;
      }
      __builtin_amdgcn_wave_barrier();
    }

    // ---- log_det: reduce over dim (4-lane groups); full-line writes ----
    ldp0 += __shfl_xor(ldp0, 1, 64);
    ldp0 += __shfl_xor(ldp0, 2, 64);
    ldp1 += __shfl_xor(ldp1, 1, 64);
    ldp1 += __shfl_xor(ldp1, 2, 64);
    if ((lane & 3) == 0) {
      float* ldo = out + (size_t)BATCH * 64;
      ldo[row0 + rl] = ldp0;
      ldo[row0 + rl + 16] = ldp1;
    }
    __builtin_amdgcn_wave_barrier();

    // ---- y2 -> out, coalesced full-line (cols 32..63 = 2nd 128B line) ----
    {
      float4* o4 = (float4*)(out + (size_t)row0 * 64);
#pragma unroll
      for (int i = 0; i < 4; ++i) {
        int flat = i * 64 + lane;        // 32 rows x 8 float4
        int r = flat >> 3, f = flat & 7;
        f16x4 v = *(const f16x4*)&y2s[r * 32 + ((f ^ (r & 7)) * 4)];
        float4 w = {(float)v[0], (float)v[1], (float)v[2], (float)v[3]};
        o4[r * 16 + 8 + f] = w;
      }
    }
  }
}

// ---------------------------------------------------------------------------
extern "C" void kernel_launch(void* const* d_in, const int* in_sizes, int n_in,
                              void* d_out, int out_size, void* d_ws, size_t ws_size,
                              hipStream_t stream) {
  const float* x  = (const float*)d_in[0];
  const float* W1 = (const float*)d_in[1];
  const float* b1 = (const float*)d_in[2];
  const float* W2 = (const float*)d_in[3];
  const float* b2 = (const float*)d_in[4];
  const float* W3 = (const float*)d_in[5];
  const float* b3 = (const float*)d_in[6];
  const float* W4 = (const float*)d_in[7];
  const float* b4 = (const float*)d_in[8];
  f16_t* wf = (f16_t*)d_ws;
  float* out = (float*)d_out;

  hipLaunchKernelGGL(convert_weights_kernel, dim3(66), dim3(256), 0, stream,
                     W1, W2, W3, W4, wf);
  hipLaunchKernelGGL(nsf_fused_kernel, dim3(NBLK), dim3(256), 0, stream,
                     x, b1, b2, b3, b4, wf, out);
}

// Round 9
// 160.252 us; speedup vs baseline: 1.0598x; 1.0598x over previous
//
#include <hip/hip_runtime.h>
#include <hip/hip_bf16.h>
#include <math.h>

typedef _Float16 f16_t;
typedef _Float16 f16x4 __attribute__((ext_vector_type(4)));
typedef _Float16 f16x8 __attribute__((ext_vector_type(8)));
typedef float f32x4 __attribute__((ext_vector_type(4)));

#define BATCH 131072
#define RPW 16                 // rows per wave
#define MTILE 64               // rows per block (4 waves)
#define NBLK (BATCH / MTILE)

// fragment-layout weight offsets in d_ws (elements, f16)
#define W1F 0
#define W2F 4096
#define W3F 20480
#define W4F 36864

#define HSTRIDE 136            // f16 elements per strip row (pad: 2-way max, free)
#define XSTRIDE 36             // f16 elements per x2 row

// ---------------------------------------------------------------------------
// Kernel A: fp32 weights -> fp16 MFMA B-fragment layout.
//   col = tile*16 + (lane&15), k = kstep*32 + (lane>>4)*8 + j
// W4 laid out as 8 chunks x 92 cols padded to 96 (6 tiles).
// ---------------------------------------------------------------------------
__global__ __launch_bounds__(256) void convert_weights_kernel(
    const float* __restrict__ W1, const float* __restrict__ W2,
    const float* __restrict__ W3, const float* __restrict__ W4,
    f16_t* __restrict__ wf) {
  int tid = blockIdx.x * 256 + threadIdx.x;
  if (tid >= 16896) return;
  int lane = tid & 63;
  int l16 = lane & 15, lhi = lane >> 4;
  const float* W; int ncols, col, k0; bool zero = false;
  if (tid < 512) {
    int n = tid >> 6;
    W = W1; ncols = 128; col = n * 16 + l16; k0 = lhi * 8;
  } else if (tid < 2560) {
    int g = tid - 512; int n = g >> 8, s = (g >> 6) & 3;
    W = W2; ncols = 128; col = n * 16 + l16; k0 = s * 32 + lhi * 8;
  } else if (tid < 4608) {
    int g = tid - 2560; int n = g >> 8, s = (g >> 6) & 3;
    W = W3; ncols = 128; col = n * 16 + l16; k0 = s * 32 + lhi * 8;
  } else {
    int g = tid - 4608; int t = g >> 8, s = (g >> 6) & 3;
    int c = t / 6, n = t - c * 6;
    int colc = n * 16 + l16;
    W = W4; ncols = 736; col = c * 92 + colc; k0 = s * 32 + lhi * 8;
    zero = (colc >= 92);
  }
  f16x8 v;
#pragma unroll
  for (int j = 0; j < 8; ++j)
    v[j] = zero ? (f16_t)0.f : (f16_t)W[(k0 + j) * ncols + col];
  *(f16x8*)(wf + (size_t)tid * 8) = v;
}

__device__ __forceinline__ float elu(float v) {
  return v > 0.f ? v : (__expf(v) - 1.f);
}

// ---------------------------------------------------------------------------
// spline for one (row, dim) task; P = 24-f16 param slot (16B-aligned).
// No softmax max-subtract (pre-acts are O(3)); divides via v_rcp_f32.
// ---------------------------------------------------------------------------
__device__ __forceinline__ void rqs_task(const f16_t* P, float xv,
                                         float& yout, float& ldout) {
  f16x8 pw = *(const f16x8*)P;
  f16x8 ph = *(const f16x8*)(P + 8);
  f16x8 pd = *(const f16x8*)(P + 16);   // [7] is pad, unused

  float ew[8], sw = 0.f;
#pragma unroll
  for (int i = 0; i < 8; ++i) { ew[i] = __expf((float)pw[i]); sw += ew[i]; }
  float invw = 0.992f * __builtin_amdgcn_rcpf(sw);
  float cw[9]; cw[0] = -3.f;
  float accw = 0.f;
#pragma unroll
  for (int i = 0; i < 8; ++i) {
    accw += 0.001f + ew[i] * invw;
    cw[i + 1] = -3.f + 6.f * accw;
  }
  cw[8] = 3.f;
  float wd[8];
#pragma unroll
  for (int i = 0; i < 8; ++i) wd[i] = cw[i + 1] - cw[i];

  float eh[8], sh = 0.f;
#pragma unroll
  for (int i = 0; i < 8; ++i) { eh[i] = __expf((float)ph[i]); sh += eh[i]; }
  float invh = 0.992f * __builtin_amdgcn_rcpf(sh);
  float ch[9]; ch[0] = -3.f;
  float acch = 0.f;
#pragma unroll
  for (int i = 0; i < 8; ++i) {
    acch += 0.001f + eh[i] * invh;
    ch[i + 1] = -3.f + 6.f * acch;
  }
  ch[8] = 3.f;
  float ht[8];
#pragma unroll
  for (int i = 0; i < 8; ++i) ht[i] = ch[i + 1] - ch[i];

  float dd[9]; dd[0] = 1.f; dd[8] = 1.f;
#pragma unroll
  for (int i = 0; i < 7; ++i) {
    float u = (float)pd[i];
    float sp = fmaxf(u, 0.f) + __logf(1.f + __expf(-fabsf(u)));
    dd[i + 1] = 0.001f + sp;
  }

  float xc = fminf(fmaxf(xv, -3.f), 3.f);
  int bin = 0;
#pragma unroll
  for (int i = 1; i < 8; ++i) bin += (xc >= cw[i]) ? 1 : 0;

  float in_cw = cw[0], in_w = wd[0], in_ch = ch[0], in_h = ht[0];
  float in_d = dd[0], in_d1 = dd[1];
#pragma unroll
  for (int i = 1; i < 8; ++i) {
    bool g = (bin >= i);
    in_cw = g ? cw[i] : in_cw;  in_w = g ? wd[i] : in_w;
    in_ch = g ? ch[i] : in_ch;  in_h = g ? ht[i] : in_h;
    in_d  = g ? dd[i] : in_d;   in_d1 = g ? dd[i + 1] : in_d1;
  }

  float rw = __builtin_amdgcn_rcpf(in_w);
  float dlt = in_h * rw;
  float th = (xc - in_cw) * rw;
  float om = 1.f - th;
  float t1 = th * om;
  float num = in_h * (dlt * th * th + in_d * t1);
  float den = dlt + (in_d + in_d1 - 2.f * dlt) * t1;
  float rden = __builtin_amdgcn_rcpf(den);
  float yo = in_ch + num * rden;
  float dn = dlt * dlt * (in_d1 * th * th + 2.f * dlt * t1 + in_d * om * om);
  float ldv = __logf(dn * rden * rden);
  bool inside = (xv >= -3.f) && (xv <= 3.f);
  yout = inside ? yo : xv;
  ldout = inside ? ldv : 0.f;
}

// ---------------------------------------------------------------------------
// middle MLP layer, in-place on the wave's own 16-row strip (f16, pad 136).
// A-fragments are register-resident before the first store (wave order).
// ---------------------------------------------------------------------------
__device__ __forceinline__ void mid_layer1(f16_t* hW,
                                           const f16_t* __restrict__ wseg,
                                           const float* __restrict__ bg,
                                           int l16, int lhi, int lane) {
  f16x8 a[4];
#pragma unroll
  for (int s = 0; s < 4; ++s)
    a[s] = *(const f16x8*)&hW[l16 * HSTRIDE + s * 32 + lhi * 8];
#pragma unroll
  for (int n = 0; n < 8; ++n) {
    f32x4 c0 = {0.f, 0.f, 0.f, 0.f};
#pragma unroll
    for (int s = 0; s < 4; ++s) {
      f16x8 b = *(const f16x8*)(wseg + (size_t)((n * 4 + s) * 64 + lane) * 8);
      c0 = __builtin_amdgcn_mfma_f32_16x16x32_f16(a[s], b, c0, 0, 0, 0);
    }
    float bias = bg[n * 16 + l16];
#pragma unroll
    for (int r = 0; r < 4; ++r)
      hW[(lhi * 4 + r) * HSTRIDE + n * 16 + l16] = (f16_t)elu(c0[r] + bias);
  }
}

// ---------------------------------------------------------------------------
// Kernel B: fused MLP + RQS spline. 16 rows/wave, 4 waves/block.
// LDS = 64*136*2 + 64*36*2 = 22016 B -> 7 blocks/CU (28 waves, 87% occ).
// Latency hiding via occupancy; syncthreads only at layer boundaries.
// ---------------------------------------------------------------------------
__global__ __launch_bounds__(256, 7) void nsf_fused_kernel(
    const float* __restrict__ x,
    const float* __restrict__ b1g, const float* __restrict__ b2g,
    const float* __restrict__ b3g, const float* __restrict__ b4g,
    const f16_t* __restrict__ wf,
    float* __restrict__ out) {
  __shared__ f16_t hH[MTILE * HSTRIDE];   // 4 wave-private 16-row strips
  __shared__ f16_t x2g[MTILE * XSTRIDE];  // staged x2 (f16)

  const int tid = threadIdx.x;
  const int lane = tid & 63;
  const int wv = tid >> 6;
  const int l16 = lane & 15, lhi = lane >> 4;
  const int row0 = blockIdx.x * MTILE + wv * RPW;   // wave's global row base
  f16_t* hW = hH + wv * RPW * HSTRIDE;              // wave's private strip
  f16_t* x2s = x2g + wv * RPW * XSTRIDE;

  // ---- stage: x rows once. x1 -> out + strip; x2 -> x2s (f16) ----
  {
    const float4* x4 = (const float4*)(x + (size_t)row0 * 64);
    float4* o4 = (float4*)(out + (size_t)row0 * 64);
#pragma unroll
    for (int i = 0; i < 4; ++i) {
      int flat = i * 64 + lane;          // 0..255 = 16 rows x 16 float4
      int r = flat >> 4, f = flat & 15;
      float4 v = x4[r * 16 + f];
      f16x4 p = {(f16_t)v.x, (f16_t)v.y, (f16_t)v.z, (f16_t)v.w};
      if (f < 8) {                       // x1 cols 0..31 (full 128B line)
        o4[r * 16 + f] = v;
        *(f16x4*)&hW[r * HSTRIDE + f * 4] = p;
      } else {                           // x2 cols 32..63
        *(f16x4*)&x2s[r * XSTRIDE + (f - 8) * 4] = p;
      }
    }
  }
  __syncthreads();

  // ---- layer 1: K=32, in-place ----
  {
    f16x8 a = *(const f16x8*)&hW[l16 * HSTRIDE + lhi * 8];
#pragma unroll
    for (int n = 0; n < 8; ++n) {
      f16x8 b = *(const f16x8*)(wf + W1F + (size_t)(n * 64 + lane) * 8);
      f32x4 c0 = {0.f, 0.f, 0.f, 0.f};
      c0 = __builtin_amdgcn_mfma_f32_16x16x32_f16(a, b, c0, 0, 0, 0);
      float bias = b1g[n * 16 + l16];
#pragma unroll
      for (int r = 0; r < 4; ++r)
        hW[(lhi * 4 + r) * HSTRIDE + n * 16 + l16] = (f16_t)elu(c0[r] + bias);
    }
  }
  __syncthreads();

  mid_layer1(hW, wf + W2F, b2g, l16, lhi, lane);   // layer 2
  __syncthreads();
  mid_layer1(hW, wf + W3F, b3g, l16, lhi, lane);   // layer 3
  __syncthreads();

  // ---- layer 4 + spline; prm + y2s alias the (now dead) strip ----
  {
    f16x8 a4[4];
#pragma unroll
    for (int s = 0; s < 4; ++s)
      a4[s] = *(const f16x8*)&hW[l16 * HSTRIDE + s * 32 + lhi * 8];
    __builtin_amdgcn_wave_barrier();

    f16_t* prW = hW;             // 64 slots x 24 f16 -> [0,1536)  (slot == lane)
    f16_t* y2s = hW + 1536;      // [16 rows][32] f16 -> [1536,2048)
    const int rl = lane >> 2, dim = lane & 3;   // this lane's (row, dim) task
    float ldp = 0.f;

    for (int c = 0; c < 8; ++c) {
      int jg = c * 4 + dim;
      float xv = (float)x2s[rl * XSTRIDE + jg];

      // GEMM4 chunk: 92 real cols (4 dims x 23) padded to 96 (6 tiles)
#pragma unroll
      for (int n = 0; n < 6; ++n) {
        f32x4 c0 = {0.f, 0.f, 0.f, 0.f};
#pragma unroll
        for (int s = 0; s < 4; ++s) {
          f16x8 b = *(const f16x8*)(wf + W4F +
                      (size_t)(((c * 6 + n) * 4 + s) * 64 + lane) * 8);
          c0 = __builtin_amdgcn_mfma_f32_16x16x32_f16(a4[s], b, c0, 0, 0, 0);
        }
        int colc = n * 16 + l16;
        if (colc < 92) {
          int dm = (colc * 90) >> 11;          // colc / 23 for colc < 92
          int j = colc - dm * 23;
          float bias = b4g[c * 92 + colc];
#pragma unroll
          for (int r = 0; r < 4; ++r)
            prW[((lhi * 4 + r) * 4 + dm) * 24 + j] = (f16_t)(c0[r] + bias);
        }
      }
      __builtin_amdgcn_wave_barrier();

      // one spline task per lane: row rl, dim = lane&3 (slot == lane)
      {
        float y0, l0;
        rqs_task(prW + lane * 24, xv, y0, l0);
        y2s[rl * 32 + jg] = (f16_t)y0;
        ldp += l0;
      }
      __builtin_amdgcn_wave_barrier();
    }

    // ---- log_det: reduce over dim (4-lane groups) ----
    ldp += __shfl_xor(ldp, 1, 64);
    ldp += __shfl_xor(ldp, 2, 64);
    if ((lane & 3) == 0)
      out[(size_t)BATCH * 64 + row0 + rl] = ldp;
    __builtin_amdgcn_wave_barrier();

    // ---- y2 -> out, coalesced full-line (cols 32..63 = 2nd 128B line) ----
    {
      float4* o4 = (float4*)(out + (size_t)row0 * 64);
#pragma unroll
      for (int i = 0; i < 2; ++i) {
        int flat = i * 64 + lane;        // 16 rows x 8 float4
        int r = flat >> 3, f = flat & 7;
        f16x4 v = *(const f16x4*)&y2s[r * 32 + f * 4];
        float4 w = {(float)v[0], (float)v[1], (float)v[2], (float)v[3]};
        o4[r * 16 + 8 + f] = w;
      }
    }
  }
}

// ---------------------------------------------------------------------------
extern "C" void kernel_launch(void* const* d_in, const int* in_sizes, int n_in,
                              void* d_out, int out_size, void* d_ws, size_t ws_size,
                              hipStream_t stream) {
  const float* x  = (const float*)d_in[0];
  const float* W1 = (const float*)d_in[1];
  const float* b1 = (const float*)d_in[2];
  const float* W2 = (const float*)d_in[3];
  const float* b2 = (const float*)d_in[4];
  const float* W3 = (const float*)d_in[5];
  const float* b3 = (const float*)d_in[6];
  const float* W4 = (const float*)d_in[7];
  const float* b4 = (const float*)d_in[8];
  f16_t* wf = (f16_t*)d_ws;
  float* out = (float*)d_out;

  hipLaunchKernelGGL(convert_weights_kernel, dim3(66), dim3(256), 0, stream,
                     W1, W2, W3, W4, wf);
  hipLaunchKernelGGL(nsf_fused_kernel, dim3(NBLK), dim3(256), 0, stream,
                     x, b1, b2, b3, b4, wf, out);
}

// Round 11
// 107.064 us; speedup vs baseline: 1.5864x; 1.4968x over previous
//
#include <hip/hip_runtime.h>
#include <hip/hip_bf16.h>
#include <math.h>

typedef _Float16 f16_t;
typedef _Float16 f16x4 __attribute__((ext_vector_type(4)));
typedef _Float16 f16x8 __attribute__((ext_vector_type(8)));
typedef float f32x4 __attribute__((ext_vector_type(4)));

#define BATCH 131072
#define MTILE 64               // rows per block (4 waves, 16 rows/wave)
#define NBLK (BATCH / MTILE)

// fragment-layout weight offsets in d_ws (elements, f16)
#define W1F 0
#define W2F 4096
#define W3F 20480
#define W4F 36864

// ---------------------------------------------------------------------------
// Kernel A: fp32 weights -> fp16 MFMA B-fragment layout.
// B-frag (mfma_f32_16x16x32_f16): lane holds 8 contiguous-k f16:
//   col = tile*16 + (lane&15), k = kstep*32 + (lane>>4)*8 + j
// W4 laid out as 8 chunks x 92 cols padded to 96 (6 tiles).
// ---------------------------------------------------------------------------
__global__ __launch_bounds__(256) void convert_weights_kernel(
    const float* __restrict__ W1, const float* __restrict__ W2,
    const float* __restrict__ W3, const float* __restrict__ W4,
    f16_t* __restrict__ wf) {
  int tid = blockIdx.x * 256 + threadIdx.x;
  if (tid >= 16896) return;
  int lane = tid & 63;
  int l16 = lane & 15, lhi = lane >> 4;
  const float* W; int ncols, col, k0; bool zero = false;
  if (tid < 512) {
    int n = tid >> 6;
    W = W1; ncols = 128; col = n * 16 + l16; k0 = lhi * 8;
  } else if (tid < 2560) {
    int g = tid - 512; int n = g >> 8, s = (g >> 6) & 3;
    W = W2; ncols = 128; col = n * 16 + l16; k0 = s * 32 + lhi * 8;
  } else if (tid < 4608) {
    int g = tid - 2560; int n = g >> 8, s = (g >> 6) & 3;
    W = W3; ncols = 128; col = n * 16 + l16; k0 = s * 32 + lhi * 8;
  } else {
    int g = tid - 4608; int t = g >> 8, s = (g >> 6) & 3;
    int c = t / 6, n = t - c * 6;
    int colc = n * 16 + l16;
    W = W4; ncols = 736; col = c * 92 + colc; k0 = s * 32 + lhi * 8;
    zero = (colc >= 92);
  }
  f16x8 v;
#pragma unroll
  for (int j = 0; j < 8; ++j)
    v[j] = zero ? (f16_t)0.f : (f16_t)W[(k0 + j) * ncols + col];
  *(f16x8*)(wf + (size_t)tid * 8) = v;
}

__device__ __forceinline__ float elu(float v) {
  return v > 0.f ? v : (__expf(v) - 1.f);
}

// ---------------------------------------------------------------------------
// spline for one (row, dim) task; P = 24-f16 param slot (16B-aligned).
// Lean form validated R5-R9: no softmax max-subtract (pre-acts are O(3)),
// all divides via v_rcp_f32, branch-free softplus, single fused log.
// ---------------------------------------------------------------------------
__device__ __forceinline__ void rqs_task(const f16_t* P, float xv,
                                         float& yout, float& ldout) {
  f16x8 pw = *(const f16x8*)P;
  f16x8 ph = *(const f16x8*)(P + 8);
  f16x8 pd = *(const f16x8*)(P + 16);   // [7] is pad, unused

  float ew[8], sw = 0.f;
#pragma unroll
  for (int i = 0; i < 8; ++i) { ew[i] = __expf((float)pw[i]); sw += ew[i]; }
  float invw = 0.992f * __builtin_amdgcn_rcpf(sw);
  float cw[9]; cw[0] = -3.f;
  float accw = 0.f;
#pragma unroll
  for (int i = 0; i < 8; ++i) {
    accw += 0.001f + ew[i] * invw;
    cw[i + 1] = -3.f + 6.f * accw;
  }
  cw[8] = 3.f;
  float wd[8];
#pragma unroll
  for (int i = 0; i < 8; ++i) wd[i] = cw[i + 1] - cw[i];

  float eh[8], sh = 0.f;
#pragma unroll
  for (int i = 0; i < 8; ++i) { eh[i] = __expf((float)ph[i]); sh += eh[i]; }
  float invh = 0.992f * __builtin_amdgcn_rcpf(sh);
  float ch[9]; ch[0] = -3.f;
  float acch = 0.f;
#pragma unroll
  for (int i = 0; i < 8; ++i) {
    acch += 0.001f + eh[i] * invh;
    ch[i + 1] = -3.f + 6.f * acch;
  }
  ch[8] = 3.f;
  float ht[8];
#pragma unroll
  for (int i = 0; i < 8; ++i) ht[i] = ch[i + 1] - ch[i];

  float dd[9]; dd[0] = 1.f; dd[8] = 1.f;
#pragma unroll
  for (int i = 0; i < 7; ++i) {
    float u = (float)pd[i];
    float sp = fmaxf(u, 0.f) + __logf(1.f + __expf(-fabsf(u)));
    dd[i + 1] = 0.001f + sp;
  }

  float xc = fminf(fmaxf(xv, -3.f), 3.f);
  int bin = 0;
#pragma unroll
  for (int i = 1; i < 8; ++i) bin += (xc >= cw[i]) ? 1 : 0;

  float in_cw = cw[0], in_w = wd[0], in_ch = ch[0], in_h = ht[0];
  float in_d = dd[0], in_d1 = dd[1];
#pragma unroll
  for (int i = 1; i < 8; ++i) {
    bool g = (bin >= i);
    in_cw = g ? cw[i] : in_cw;  in_w = g ? wd[i] : in_w;
    in_ch = g ? ch[i] : in_ch;  in_h = g ? ht[i] : in_h;
    in_d  = g ? dd[i] : in_d;   in_d1 = g ? dd[i + 1] : in_d1;
  }

  float rw = __builtin_amdgcn_rcpf(in_w);
  float dlt = in_h * rw;
  float th = (xc - in_cw) * rw;
  float om = 1.f - th;
  float t1 = th * om;
  float num = in_h * (dlt * th * th + in_d * t1);
  float den = dlt + (in_d + in_d1 - 2.f * dlt) * t1;
  float rden = __builtin_amdgcn_rcpf(den);
  float yo = in_ch + num * rden;
  float dn = dlt * dlt * (in_d1 * th * th + 2.f * dlt * t1 + in_d * om * om);
  float ldv = __logf(dn * rden * rden);
  bool inside = (xv >= -3.f) && (xv <= 3.f);
  yout = inside ? yo : xv;
  ldout = inside ? ldv : 0.f;
}

// ---------------------------------------------------------------------------
// middle MLP layer (R3 form): in-place on the wave's 16-row strip of hH.
// A-fragments are register-resident before the first store.
// ---------------------------------------------------------------------------
__device__ __forceinline__ void mid_layer_ip(f16_t* hH,
                                             const f16_t* __restrict__ wseg,
                                             const float* __restrict__ bg,
                                             int wv, int l16, int lhi, int lane) {
  f16x8 a[4];
#pragma unroll
  for (int s = 0; s < 4; ++s)
    a[s] = *(const f16x8*)&hH[(wv * 16 + l16) * 136 + s * 32 + lhi * 8];
#pragma unroll
  for (int n = 0; n < 8; ++n) {
    f32x4 acc = {0.f, 0.f, 0.f, 0.f};
#pragma unroll
    for (int s = 0; s < 4; ++s) {
      f16x8 b = *(const f16x8*)(wseg + (size_t)((n * 4 + s) * 64 + lane) * 8);
      acc = __builtin_amdgcn_mfma_f32_16x16x32_f16(a[s], b, acc, 0, 0, 0);
    }
    float bias = bg[n * 16 + l16];
#pragma unroll
    for (int r = 0; r < 4; ++r)
      hH[(wv * 16 + lhi * 4 + r) * 136 + n * 16 + l16] =
          (f16_t)elu(acc[r] + bias);
  }
}

// ---------------------------------------------------------------------------
// Kernel B (R3 skeleton): fused MLP + RQS spline. 64 rows/block, 4 waves,
// block-wide __syncthreads; separate (non-aliased) prm/x2s buffers; direct
// scalar y2 global stores (R3-measured WRITE = ideal at this occupancy).
// LDS: 17408 (hH) + 12288 (prm f16) + 8448 (x2s f32) = 38144 B -> 4 blk/CU.
// ---------------------------------------------------------------------------
__global__ __launch_bounds__(256, 4) void nsf_fused_kernel(
    const float* __restrict__ x,
    const float* __restrict__ b1g, const float* __restrict__ b2g,
    const float* __restrict__ b3g, const float* __restrict__ b4g,
    const f16_t* __restrict__ wf,
    float* __restrict__ out) {
  __shared__ f16_t hH[MTILE * 136];       // hidden state, in-place across layers
  __shared__ f16_t prm[MTILE * 4 * 24];   // spline params chunk, f16 24-slots
  __shared__ float x2s[MTILE * 33];       // x2 tile, fp32

  const int tid = threadIdx.x;
  const int lane = tid & 63;
  const int wv = tid >> 6;
  const int l16 = lane & 15, lhi = lane >> 4;
  const int row0 = blockIdx.x * MTILE;

  // ---- stage x: x1 -> out + hH (f16), x2 -> x2s (f32) ----
  {
    const float4* x4 = (const float4*)(x + (size_t)row0 * 64);
    float4* o4 = (float4*)(out + (size_t)row0 * 64);
#pragma unroll
    for (int it = 0; it < 4; ++it) {
      int idx = tid + it * 256;          // 0..1023 = 64 rows x 16 float4
      int row = idx >> 4, q = idx & 15;
      float4 v = x4[row * 16 + q];
      if (q < 8) {                       // x1 cols 0..31
        o4[row * 16 + q] = v;
        f16x4 p = {(f16_t)v.x, (f16_t)v.y, (f16_t)v.z, (f16_t)v.w};
        *(f16x4*)&hH[row * 136 + q * 4] = p;
      } else {                           // x2 cols 32..63
        int cb = row * 33 + (q - 8) * 4;
        x2s[cb + 0] = v.x; x2s[cb + 1] = v.y;
        x2s[cb + 2] = v.z; x2s[cb + 3] = v.w;
      }
    }
  }
  __syncthreads();

  // ---- layer 1: (64x32)@(32x128), K=32, in-place ----
  {
    f16x8 a = *(const f16x8*)&hH[(wv * 16 + l16) * 136 + lhi * 8];
#pragma unroll
    for (int n = 0; n < 8; ++n) {
      f16x8 b = *(const f16x8*)(wf + W1F + (size_t)(n * 64 + lane) * 8);
      f32x4 acc = {0.f, 0.f, 0.f, 0.f};
      acc = __builtin_amdgcn_mfma_f32_16x16x32_f16(a, b, acc, 0, 0, 0);
      float bias = b1g[n * 16 + l16];
#pragma unroll
      for (int r = 0; r < 4; ++r)
        hH[(wv * 16 + lhi * 4 + r) * 136 + n * 16 + l16] =
            (f16_t)elu(acc[r] + bias);
    }
  }
  __syncthreads();

  mid_layer_ip(hH, wf + W2F, b2g, wv, l16, lhi, lane);   // layer 2
  __syncthreads();
  mid_layer_ip(hH, wf + W3F, b3g, wv, l16, lhi, lane);   // layer 3
  __syncthreads();

  // ---- layer 4 + spline, 8 chunks of 4 spline-dims each ----
  {
    f16x8 a4[4];
#pragma unroll
    for (int s = 0; s < 4; ++s)
      a4[s] = *(const f16x8*)&hH[(wv * 16 + l16) * 136 + s * 32 + lhi * 8];

    const int srow = tid >> 2;   // spline row 0..63
    const int sjj = tid & 3;     // chunk-local spline dim
    float ldp = 0.f;

    for (int c = 0; c < 8; ++c) {
      // GEMM4 chunk: 92 real cols (4 dims x 23) padded to 96 (6 tiles)
#pragma unroll
      for (int n = 0; n < 6; ++n) {
        f32x4 acc = {0.f, 0.f, 0.f, 0.f};
#pragma unroll
        for (int s = 0; s < 4; ++s) {
          f16x8 b = *(const f16x8*)(wf + W4F +
                      (size_t)(((c * 6 + n) * 4 + s) * 64 + lane) * 8);
          acc = __builtin_amdgcn_mfma_f32_16x16x32_f16(a4[s], b, acc, 0, 0, 0);
        }
        int colc = n * 16 + l16;
        if (colc < 92) {
          int dm = (colc * 90) >> 11;          // colc / 23 for colc < 92
          int j = colc - dm * 23;
          float bias = b4g[c * 92 + colc];
#pragma unroll
          for (int r = 0; r < 4; ++r)
            prm[((wv * 16 + lhi * 4 + r) * 4 + dm) * 24 + j] =
                (f16_t)(acc[r] + bias);
        }
      }
      __syncthreads();

      // ---- spline: one (row, dim) task per thread ----
      {
        int jg = c * 4 + sjj;
        float xv = x2s[srow * 33 + jg];
        float y0, l0;
        rqs_task(prm + (srow * 4 + sjj) * 24, xv, y0, l0);
        out[(size_t)(row0 + srow) * 64 + 32 + jg] = y0;
        ldp += l0;
      }
      __syncthreads();
    }

    // ---- log_det: quad reduce over sjj ----
    ldp += __shfl_xor(ldp, 1, 64);
    ldp += __shfl_xor(ldp, 2, 64);
    if ((tid & 3) == 0)
      out[(size_t)BATCH * 64 + row0 + srow] = ldp;
  }
}

// ---------------------------------------------------------------------------
extern "C" void kernel_launch(void* const* d_in, const int* in_sizes, int n_in,
                              void* d_out, int out_size, void* d_ws, size_t ws_size,
                              hipStream_t stream) {
  const float* x  = (const float*)d_in[0];
  const float* W1 = (const float*)d_in[1];
  const float* b1 = (const float*)d_in[2];
  const float* W2 = (const float*)d_in[3];
  const float* b2 = (const float*)d_in[4];
  const float* W3 = (const float*)d_in[5];
  const float* b3 = (const float*)d_in[6];
  const float* W4 = (const float*)d_in[7];
  const float* b4 = (const float*)d_in[8];
  f16_t* wf = (f16_t*)d_ws;
  float* out = (float*)d_out;

  hipLaunchKernelGGL(convert_weights_kernel, dim3(66), dim3(256), 0, stream,
                     W1, W2, W3, W4, wf);
  hipLaunchKernelGGL(nsf_fused_kernel, dim3(NBLK), dim3(256), 0, stream,
                     x, b1, b2, b3, b4, wf, out);
}